// Round 6
// baseline (473.265 us; speedup 1.0000x reference)
//
#include <hip/hip_runtime.h>
#include <hip/hip_bf16.h>
#include <cstdint>
#include <cstddef>

#define Bb 4
#define Nn 2048
#define Cc_ 1024
#define Hh 16
#define Dd 64
#define Mm (Bb*Nn)

typedef unsigned short u16;
typedef unsigned int u32;
typedef __attribute__((ext_vector_type(8))) short short8;
typedef __attribute__((ext_vector_type(4))) short s16x4;
typedef __attribute__((ext_vector_type(4))) float f32x4;
typedef __attribute__((ext_vector_type(16))) float f32x16;
typedef __attribute__((ext_vector_type(2))) float f32x2;
typedef __attribute__((ext_vector_type(4))) unsigned short u16x4;

__device__ __forceinline__ float bf2f(u16 v){ u32 u = ((u32)v)<<16; return __builtin_bit_cast(float, u); }
__device__ __forceinline__ u16 f2bf(float f){ u32 u = __builtin_bit_cast(u32, f); return (u16)((u + 0x7FFFu + ((u>>16)&1u))>>16); }

using gp_t = const __attribute__((address_space(1))) u32*;
using lp_t = __attribute__((address_space(3))) u32*;
__device__ __forceinline__ void gld16(const void* g, void* l){
  __builtin_amdgcn_global_load_lds((gp_t)g, (lp_t)l, 16, 0, 0);
}

__device__ __forceinline__ u32 cvtpk(float lo, float hi){
  u32 r; asm("v_cvt_pk_bf16_f32 %0, %1, %2" : "=v"(r) : "v"(lo), "v"(hi)); return r;
}

// ---------------- transpose + f32->bf16 convert: out[Ncols][R] = in[R][Ncols]^T
__global__ __launch_bounds__(256) void kT_cvt(const float* __restrict__ in, u16* __restrict__ out,
                                              int R, int Ncols){
  __shared__ float tile[64][65];
  const int c0 = blockIdx.x*64, r0 = blockIdx.y*64;
  const int t = threadIdx.x;
  #pragma unroll
  for(int i=0;i<16;i++){ int e = i*256 + t; int r = e>>6, c = e&63;
    tile[r][c] = in[(size_t)(r0+r)*Ncols + c0 + c]; }
  __syncthreads();
  #pragma unroll
  for(int i=0;i<16;i++){ int e = i*256 + t; int cc = e>>6, r = e&63;
    out[(size_t)(c0+cc)*R + r0 + r] = f2bf(tile[r][cc]); }
}

// ---------------- f32 -> bf16 elementwise (vectorized)
__global__ __launch_bounds__(256) void k_cvt(const float* __restrict__ in, u16* __restrict__ o, int n){
  int i = (blockIdx.x*256 + threadIdx.x)*4;
  if(i >= n) return;
  f32x4 v = *(const f32x4*)(in + i);
  u16x4 r;
  #pragma unroll
  for(int j=0;j<4;j++) r[j] = f2bf(v[j]);
  *(u16x4*)(o + i) = r;
}

// ---------------- rope cos/sin table: tab[n*32+i] = {cos, sin}
__global__ __launch_bounds__(256) void k_ropetab(float* __restrict__ tab){
  int idx = blockIdx.x*256 + threadIdx.x;   // 0..65535
  int n = idx>>5, i = idx&31;
  float invf = powf(10000.f, -(float)i*(1.f/32.f));
  float ang = (float)n * invf;
  float s_, c_;
  sincosf(ang, &s_, &c_);
  f32x2 cs; cs[0] = c_; cs[1] = s_;
  ((f32x2*)tab)[idx] = cs;
}

// ---------------- LN(x) * (1+scale) + shift -> h (bf16); one block per row
__global__ __launch_bounds__(256) void k_ln_mod(const float* __restrict__ x, const float* __restrict__ ss,
                                                u16* __restrict__ h){
  const int r = blockIdx.x, t = threadIdx.x;
  const float* xr = x + (size_t)r*Cc_;
  f32x4 xv = *(const f32x4*)(xr + t*4);
  float s = xv[0]+xv[1]+xv[2]+xv[3];
  float s2 = xv[0]*xv[0]+xv[1]*xv[1]+xv[2]*xv[2]+xv[3]*xv[3];
  #pragma unroll
  for(int off=1; off<64; off<<=1){ s += __shfl_xor(s, off); s2 += __shfl_xor(s2, off); }
  __shared__ float red[8];
  int w = t>>6, l = t&63;
  if(l==0){ red[w] = s; red[4+w] = s2; }
  __syncthreads();
  s = red[0]+red[1]+red[2]+red[3];
  s2 = red[4]+red[5]+red[6]+red[7];
  float mu = s * (1.f/Cc_);
  float rstd = rsqrtf(s2*(1.f/Cc_) - mu*mu + 1e-5f);
  f32x4 sc = *(const f32x4*)(ss + (size_t)r*2*Cc_ + t*4);
  f32x4 sh = *(const f32x4*)(ss + (size_t)r*2*Cc_ + Cc_ + t*4);
  u16x4 o;
  #pragma unroll
  for(int j=0;j<4;j++){ float hv = (xv[j]-mu)*rstd*(1.f+sc[j]) + sh[j]; o[j] = f2bf(hv); }
  *(u16x4*)(h + (size_t)r*Cc_ + t*4) = o;
}

// ---------------- per-head LN over D=64 + rope, in place; one wave per row (R1-proven form)
__global__ __launch_bounds__(256) void k_lnrope(u16* __restrict__ qp, u16* __restrict__ kp,
                                                const float* __restrict__ tab){
  const int w = threadIdx.x>>6, l = threadIdx.x&63;
  const int row = blockIdx.x*4 + w;                 // 0..B*H*N-1
  u16* p = (blockIdx.y ? kp : qp) + (size_t)row*Dd;
  const int n = row & (Nn-1);
  float v = bf2f(p[l]);
  float s = v, s2 = v*v;
  #pragma unroll
  for(int off=1; off<64; off<<=1){ s += __shfl_xor(s, off); s2 += __shfl_xor(s2, off); }
  float mu = s*(1.f/64.f);
  float rstd = rsqrtf(s2*(1.f/64.f) - mu*mu + 1e-5f);
  float tv = (v - mu)*rstd;
  float pv = __shfl_xor(tv, 32);
  f32x2 cs = ((const f32x2*)tab)[n*32 + (l&31)];
  float o = (l < 32) ? (tv*cs[0] - pv*cs[1]) : (pv*cs[1] + tv*cs[0]);
  p[l] = f2bf(o);
}

// ---------------- V (bh,N,D) -> VT (bh,D,N)
__global__ __launch_bounds__(256) void k_vT(const u16* __restrict__ v, u16* __restrict__ vt){
  __shared__ u32 tile[64][65];
  const int bh = blockIdx.y, n0 = blockIdx.x*64;
  const int t = threadIdx.x;
  const u16* src = v + ((size_t)bh*Nn + n0)*Dd;
  #pragma unroll
  for(int i=0;i<16;i++){ int e = i*256+t; tile[e>>6][e&63] = src[e]; }
  __syncthreads();
  #pragma unroll
  for(int i=0;i<16;i++){ int e = i*256+t; int d = e>>6, n = e&63;
    vt[((size_t)bh*Dd + d)*Nn + n0 + n] = (u16)tile[n][d]; }
}

// ---------------- shared bt-GEMM: C(M x Nc) = A(M x K) @ BT(Nc x K)^T
// T1 bijective XCD swizzle on the flattened block id (all grids are %8==0)
template<int MODE>
__global__ __launch_bounds__(256) void k_gemm(
    const u16* __restrict__ A, const u16* __restrict__ BT, int K, int Nc,
    const float* __restrict__ bias, float* __restrict__ outf,
    u16* __restrict__ qo, u16* __restrict__ ko, u16* __restrict__ vo,
    const float* __restrict__ addend)
{
  __shared__ u16 sA[128*64];
  __shared__ u16 sB[128*64];
  const int t = threadIdx.x, w = t>>6;
  const int lr = t&15, lg = (t&63)>>4;
  const int gx = gridDim.x;
  const int nwg = gx*gridDim.y;
  const int fid = blockIdx.y*gx + blockIdx.x;
  const int sid = (fid&7)*(nwg>>3) + (fid>>3);
  const int row0 = (sid/gx)*128, col0 = (sid%gx)*128;
  const int wm = w>>1, wn = w&1;
  f32x4 acc[4][4] = {};
  for(int k0=0; k0<K; k0+=64){
    #pragma unroll
    for(int c=0;c<4;c++){
      int e = (c*256+t)*8;
      int r = e>>6, ch = (e>>3)&7;
      int sw = ((ch ^ (r&7))<<3);
      const u16* ga = A + (size_t)(row0+r)*K + k0 + sw;
      gld16(ga, (char*)sA + (c*256 + w*64)*16);
      const u16* gb = BT + (size_t)(col0+r)*K + k0 + sw;
      gld16(gb, (char*)sB + (c*256 + w*64)*16);
    }
    asm volatile("s_waitcnt vmcnt(0)" ::: "memory");
    __syncthreads();
    #pragma unroll
    for(int kk=0;kk<2;kk++){
      short8 af[4], bfr[4];
      #pragma unroll
      for(int mi=0;mi<4;mi++){
        int r = wm*64 + mi*16 + lr;
        af[mi] = *(const short8*)(sA + r*64 + (((kk*4+lg) ^ (r&7))<<3));
      }
      #pragma unroll
      for(int ni=0;ni<4;ni++){
        int r = wn*64 + ni*16 + lr;
        bfr[ni] = *(const short8*)(sB + r*64 + (((kk*4+lg) ^ (r&7))<<3));
      }
      #pragma unroll
      for(int mi=0;mi<4;mi++)
        #pragma unroll
        for(int ni=0;ni<4;ni++)
          acc[mi][ni] = __builtin_amdgcn_mfma_f32_16x16x32_bf16(af[mi], bfr[ni], acc[mi][ni], 0,0,0);
    }
    __syncthreads();
  }
  #pragma unroll
  for(int mi=0;mi<4;mi++){
    #pragma unroll
    for(int ni=0;ni<4;ni++){
      #pragma unroll
      for(int j=0;j<4;j++){
        int grow = row0 + wm*64 + mi*16 + lg*4 + j;
        int gcol = col0 + wn*64 + ni*16 + lr;
        float val = acc[mi][ni][j];
        if(MODE==0){
          outf[(size_t)grow*Nc + gcol] = val + bias[gcol];
        } else if(MODE==1){
          int tt = gcol>>10, hh = (gcol>>6)&15, dd = gcol&63;
          int b = grow>>11, n = grow&(Nn-1);
          size_t idx = (((size_t)(b*Hh+hh))*Nn + n)*Dd + dd;
          u16 bv = f2bf(val);
          if(tt==0) qo[idx]=bv; else if(tt==1) ko[idx]=bv; else vo[idx]=bv;
        } else {
          size_t idx = (size_t)grow*Nc + gcol;
          outf[idx] = val + addend[idx];
        }
      }
    }
  }
}

// ---------------- flash attention, swapped-QK^T in-register softmax (numerics = R5-proven)
// Round-6 changes are pure codegen: hoisted LDS offsets, unroll-by-2 so buf is compile-time
// (ds_read gets constant offset: immediates), precomputed staging pointers, max3-style max chain.
__global__ __launch_bounds__(256,3) void k_attn(
    const u16* __restrict__ Q, const u16* __restrict__ Kb,
    const u16* __restrict__ VT, u16* __restrict__ obf, float* __restrict__ of)
{
  __shared__ u16 sK[2][4096];
  __shared__ u16 sV[2][4096];
  const int t = threadIdx.x, w = t>>6, l = t&63;
  const int srow = l&31, hi = l>>5;
  const int id = blockIdx.x;
  const int bh = ((id&7)<<3) | ((id>>3)&7);   // 8 bh per XCD: K/V stays in one L2
  const int q0 = (id>>6)*128;
  const u16* qb = Q  + (size_t)bh*Nn*Dd;
  const u16* kg = Kb + (size_t)bh*Nn*Dd;
  const u16* vg = VT + (size_t)bh*Dd*Nn;

  // Q fragments (B-operand: col=srow -> q, slot (hi,j) -> d = c*16 + hi*8 + j)
  short8 qf[4];
  #pragma unroll
  for(int c=0;c<4;c++)
    qf[c] = *(const short8*)(qb + (size_t)(q0 + w*32 + srow)*Dd + c*16 + hi*8);

  f32x16 o0 = {}, o1 = {};
  float mrun = -3e38f, lsum = 0.f;
  const float cl2 = 0.18033688011112042f;   // (1/sqrt(64)) * log2(e)

  const int grow8 = l>>3;
  const int gc = (l&7) ^ grow8;
  const int x7 = l&7;

  // hoisted per-lane LDS byte offsets (loop-invariant)
  int koff[4], voff[8];
  #pragma unroll
  for(int c=0;c<4;c++)  koff[c]  = srow*128 + (((c*2+hi)^x7)<<4);
  #pragma unroll
  for(int cc=0;cc<8;cc++) voff[cc] = srow*128 + ((cc^x7)<<4) + hi*8;

  // per-lane staging source pointer + strides (waves 0,1 stage K; 2,3 stage V)
  const u16* gst; int sI, adv;
  if(w < 2){ gst = kg + (size_t)(w*4)*512 + grow8*64 + gc*8;        sI = 512;   adv = 4096; }
  else     { gst = vg + ((size_t)(w*4-8)*8 + grow8)*Nn + gc*8;      sI = 16384; adv = 64;   }
  char* myLds0 = (w < 2) ? ((char*)&sK[0][0] + w*4096) : ((char*)&sV[0][0] + (w-2)*4096);
  char* myLds1 = myLds0 + 8192;

  auto stage = [&](char* dst){
    #pragma unroll
    for(int i=0;i<4;i++)
      gld16(gst + (size_t)i*sI, dst + i*1024);
    gst += adv;
  };

  auto compute = [&](int BUF){   // BUF is a literal at each call site -> folds after inlining
    const char* sKb = (const char*)&sK[BUF][0];
    const char* sVb = (const char*)&sV[BUF][0];
    // ---- QK^T: s0/s1 = S^T for kv 0..31 / 32..63 of this tile (raw scores)
    f32x16 s0 = {}, s1 = {};
    #pragma unroll
    for(int c=0;c<4;c++){
      short8 kf0 = *(const short8*)(sKb + koff[c]);
      short8 kf1 = *(const short8*)(sKb + koff[c] + 4096);
      s0 = __builtin_amdgcn_mfma_f32_32x32x16_bf16(kf0, qf[c], s0, 0,0,0);
      s1 = __builtin_amdgcn_mfma_f32_32x32x16_bf16(kf1, qf[c], s1, 0,0,0);
    }
    // ---- online softmax (exp2 domain after *cl2); max3-shaped chain
    float pm = fmaxf(s0[0], s0[1]);
    #pragma unroll
    for(int r=2;r<16;r+=2) pm = fmaxf(pm, fmaxf(s0[r], s0[r+1]));
    #pragma unroll
    for(int r=0;r<16;r+=2) pm = fmaxf(pm, fmaxf(s1[r], s1[r+1]));
    pm = fmaxf(pm, __shfl_xor(pm, 32));
    pm *= cl2;
    if(!__all(pm <= mrun + 8.f)){           // defer-max (T13)
      float mn = fmaxf(mrun, pm);
      float al = exp2f(mrun - mn);
      mrun = mn; lsum *= al;
      #pragma unroll
      for(int r=0;r<16;r++){ o0[r] *= al; o1[r] *= al; }
    }
    float rs = 0.f;
    #pragma unroll
    for(int r=0;r<16;r++){
      float p0 = exp2f(__builtin_fmaf(s0[r], cl2, -mrun)); s0[r] = p0;
      float p1 = exp2f(__builtin_fmaf(s1[r], cl2, -mrun)); s1[r] = p1;
      rs += p0 + p1;
    }
    rs += __shfl_xor(rs, 32);
    lsum += rs;
    // ---- PV: O^T += V-frag x P-frag with lane-local k-slices
    #pragma unroll
    for(int kb=0;kb<2;kb++){
      const f32x16& sp = kb ? s1 : s0;
      union { u32 wd[4]; short8 v; } pA, pB;
      pA.wd[0]=cvtpk(sp[0],sp[1]);   pA.wd[1]=cvtpk(sp[2],sp[3]);
      pA.wd[2]=cvtpk(sp[4],sp[5]);   pA.wd[3]=cvtpk(sp[6],sp[7]);
      pB.wd[0]=cvtpk(sp[8],sp[9]);   pB.wd[1]=cvtpk(sp[10],sp[11]);
      pB.wd[2]=cvtpk(sp[12],sp[13]); pB.wd[3]=cvtpk(sp[14],sp[15]);
      #pragma unroll
      for(int db=0;db<2;db++){
        union { s16x4 h[2]; short8 v; } vA, vB;
        vA.h[0] = *(const s16x4*)(sVb + voff[kb*4+0] + db*4096);
        vA.h[1] = *(const s16x4*)(sVb + voff[kb*4+1] + db*4096);
        vB.h[0] = *(const s16x4*)(sVb + voff[kb*4+2] + db*4096);
        vB.h[1] = *(const s16x4*)(sVb + voff[kb*4+3] + db*4096);
        if(db==0){
          o0 = __builtin_amdgcn_mfma_f32_32x32x16_bf16(vA.v, pA.v, o0, 0,0,0);
          o0 = __builtin_amdgcn_mfma_f32_32x32x16_bf16(vB.v, pB.v, o0, 0,0,0);
        } else {
          o1 = __builtin_amdgcn_mfma_f32_32x32x16_bf16(vA.v, pA.v, o1, 0,0,0);
          o1 = __builtin_amdgcn_mfma_f32_32x32x16_bf16(vB.v, pB.v, o1, 0,0,0);
        }
      }
    }
  };

  // prologue: stage tile 0 into buf0
  stage(myLds0);
  asm volatile("s_waitcnt vmcnt(0)" ::: "memory");
  __syncthreads();

  #pragma unroll 1
  for(int m=0;m<16;m++){
    stage(myLds1);                 // tile 2m+1 -> buf1
    compute(0);                    // tile 2m from buf0
    asm volatile("s_waitcnt vmcnt(0)" ::: "memory");
    __syncthreads();
    if(m < 15) stage(myLds0);      // tile 2m+2 -> buf0
    compute(1);                    // tile 2m+1 from buf1
    asm volatile("s_waitcnt vmcnt(0)" ::: "memory");
    __syncthreads();
  }

  // ---- epilogue: lane owns O[q=q0+w*32+srow][d = (r&3)+8(r>>2)+4hi + 32db]
  float rl = 1.0f / lsum;
  const int n = q0 + w*32 + srow;
  const int b = bh>>4, hh = bh&15;
  size_t base = ((size_t)(b*Nn + n))*Cc_ + hh*Dd;
  #pragma unroll
  for(int db=0;db<2;db++){
    const f32x16& oo = db ? o1 : o0;
    #pragma unroll
    for(int mb=0;mb<4;mb++){
      int d0 = db*32 + mb*8 + hi*4;
      f32x4 v4; u16x4 h4;
      #pragma unroll
      for(int j=0;j<4;j++){ float v = oo[mb*4+j]*rl; v4[j] = v; h4[j] = f2bf(v); }
      *(f32x4*)(of + base + d0) = v4;
      *(u16x4*)(obf + base + d0) = h4;
    }
  }
}

extern "C" void kernel_launch(void* const* d_in, const int* in_sizes, int n_in,
                              void* d_out, int out_size, void* d_ws, size_t ws_size,
                              hipStream_t stream){
  const float* x      = (const float*)d_in[0];
  const float* emb    = (const float*)d_in[1];
  const float* emb_w  = (const float*)d_in[2];
  const float* emb_b  = (const float*)d_in[3];
  const float* proj_w = (const float*)d_in[4];
  const float* out_w  = (const float*)d_in[5];
  float* out = (float*)d_out;
  char* ws = (char*)d_ws;
  size_t off = 0;
  auto alloc = [&](size_t bytes)->char*{ char* p = ws + off; off += (bytes+255)&~(size_t)255; return p; };

  u16*  embbf = (u16*)alloc((size_t)Mm*Cc_*2);        // 16MB; reused as vT after GEMM1
  u16*  wT_e  = (u16*)alloc((size_t)2*Cc_*Cc_*2);     // 4MB
  u16*  wT_p  = (u16*)alloc((size_t)3*Cc_*Cc_*2);     // 6MB
  u16*  wT_o  = (u16*)alloc((size_t)Cc_*Cc_*2);       // 2MB
  float* ss   = (float*)alloc((size_t)Mm*2*Cc_*4);    // 64MB; reused as of+obf after ln_mod
  u16*  h     = (u16*)alloc((size_t)Mm*Cc_*2);        // 16MB
  u16*  qB    = (u16*)alloc((size_t)Mm*Cc_*2);        // 16MB
  u16*  kB    = (u16*)alloc((size_t)Mm*Cc_*2);        // 16MB
  u16*  vB    = (u16*)alloc((size_t)Mm*Cc_*2);        // 16MB
  float* tab  = (float*)alloc((size_t)Nn*32*8);       // 512KB

  u16*  vT  = embbf;                                  // alias (embbf dead after GEMM1)
  float* of  = ss;                                    // alias (ss dead after ln_mod)
  u16*  obf = (u16*)((char*)ss + (size_t)Mm*Cc_*4);

  kT_cvt<<<dim3(32,16),256,0,stream>>>(emb_w,  wT_e, Cc_, 2*Cc_);
  kT_cvt<<<dim3(48,16),256,0,stream>>>(proj_w, wT_p, Cc_, 3*Cc_);
  kT_cvt<<<dim3(16,16),256,0,stream>>>(out_w,  wT_o, Cc_, Cc_);
  k_cvt<<<8192,256,0,stream>>>(emb, embbf, Mm*Cc_);
  k_ropetab<<<256,256,0,stream>>>(tab);
  k_gemm<0><<<dim3(16,64),256,0,stream>>>(embbf, wT_e, Cc_, 2*Cc_, emb_b, ss,
                                          nullptr,nullptr,nullptr, nullptr);
  k_ln_mod<<<Mm,256,0,stream>>>(x, ss, h);
  k_gemm<1><<<dim3(24,64),256,0,stream>>>(h, wT_p, Cc_, 3*Cc_, nullptr, nullptr,
                                          qB, kB, vB, nullptr);
  k_lnrope<<<dim3(32768,2),256,0,stream>>>(qB, kB, tab);
  k_vT<<<dim3(32,64),256,0,stream>>>(vB, vT);
  k_attn<<<1024,256,0,stream>>>(qB, kB, vT, obf, of);
  k_gemm<2><<<dim3(8,64),256,0,stream>>>(obf, wT_o, Cc_, Cc_, nullptr, out,
                                         nullptr,nullptr,nullptr, of);
}

// Round 8
// 458.309 us; speedup vs baseline: 1.0326x; 1.0326x over previous
//
#include <hip/hip_runtime.h>
#include <hip/hip_bf16.h>
#include <cstdint>
#include <cstddef>

#define Bb 4
#define Nn 2048
#define Cc_ 1024
#define Hh 16
#define Dd 64
#define Mm (Bb*Nn)

typedef unsigned short u16;
typedef unsigned int u32;
typedef __attribute__((ext_vector_type(8))) short short8;
typedef __attribute__((ext_vector_type(4))) short s16x4;
typedef __attribute__((ext_vector_type(4))) float f32x4;
typedef __attribute__((ext_vector_type(16))) float f32x16;
typedef __attribute__((ext_vector_type(2))) float f32x2;
typedef __attribute__((ext_vector_type(4))) unsigned short u16x4;

__device__ __forceinline__ float bf2f(u16 v){ u32 u = ((u32)v)<<16; return __builtin_bit_cast(float, u); }
__device__ __forceinline__ u16 f2bf(float f){ u32 u = __builtin_bit_cast(u32, f); return (u16)((u + 0x7FFFu + ((u>>16)&1u))>>16); }

using gp_t = const __attribute__((address_space(1))) u32*;
using lp_t = __attribute__((address_space(3))) u32*;
__device__ __forceinline__ void gld16(const void* g, void* l){
  __builtin_amdgcn_global_load_lds((gp_t)g, (lp_t)l, 16, 0, 0);
}

__device__ __forceinline__ u32 cvtpk(float lo, float hi){
  u32 r; asm("v_cvt_pk_bf16_f32 %0, %1, %2" : "=v"(r) : "v"(lo), "v"(hi)); return r;
}

// ---------------- transpose + f32->bf16 convert: out[Ncols][R] = in[R][Ncols]^T
__global__ __launch_bounds__(256) void kT_cvt(const float* __restrict__ in, u16* __restrict__ out,
                                              int R, int Ncols){
  __shared__ float tile[64][65];
  const int c0 = blockIdx.x*64, r0 = blockIdx.y*64;
  const int t = threadIdx.x;
  #pragma unroll
  for(int i=0;i<16;i++){ int e = i*256 + t; int r = e>>6, c = e&63;
    tile[r][c] = in[(size_t)(r0+r)*Ncols + c0 + c]; }
  __syncthreads();
  #pragma unroll
  for(int i=0;i<16;i++){ int e = i*256 + t; int cc = e>>6, r = e&63;
    out[(size_t)(c0+cc)*R + r0 + r] = f2bf(tile[r][cc]); }
}

// ---------------- f32 -> bf16 elementwise (vectorized)
__global__ __launch_bounds__(256) void k_cvt(const float* __restrict__ in, u16* __restrict__ o, int n){
  int i = (blockIdx.x*256 + threadIdx.x)*4;
  if(i >= n) return;
  f32x4 v = *(const f32x4*)(in + i);
  u16x4 r;
  #pragma unroll
  for(int j=0;j<4;j++) r[j] = f2bf(v[j]);
  *(u16x4*)(o + i) = r;
}

// ---------------- rope cos/sin table: tab[n*32+i] = {cos, sin}
__global__ __launch_bounds__(256) void k_ropetab(float* __restrict__ tab){
  int idx = blockIdx.x*256 + threadIdx.x;   // 0..65535
  int n = idx>>5, i = idx&31;
  float invf = powf(10000.f, -(float)i*(1.f/32.f));
  float ang = (float)n * invf;
  float s_, c_;
  sincosf(ang, &s_, &c_);
  f32x2 cs; cs[0] = c_; cs[1] = s_;
  ((f32x2*)tab)[idx] = cs;
}

// ---------------- LN(x) * (1+scale) + shift -> h (bf16); one block per row
__global__ __launch_bounds__(256) void k_ln_mod(const float* __restrict__ x, const float* __restrict__ ss,
                                                u16* __restrict__ h){
  const int r = blockIdx.x, t = threadIdx.x;
  const float* xr = x + (size_t)r*Cc_;
  f32x4 xv = *(const f32x4*)(xr + t*4);
  float s = xv[0]+xv[1]+xv[2]+xv[3];
  float s2 = xv[0]*xv[0]+xv[1]*xv[1]+xv[2]*xv[2]+xv[3]*xv[3];
  #pragma unroll
  for(int off=1; off<64; off<<=1){ s += __shfl_xor(s, off); s2 += __shfl_xor(s2, off); }
  __shared__ float red[8];
  int w = t>>6, l = t&63;
  if(l==0){ red[w] = s; red[4+w] = s2; }
  __syncthreads();
  s = red[0]+red[1]+red[2]+red[3];
  s2 = red[4]+red[5]+red[6]+red[7];
  float mu = s * (1.f/Cc_);
  float rstd = rsqrtf(s2*(1.f/Cc_) - mu*mu + 1e-5f);
  f32x4 sc = *(const f32x4*)(ss + (size_t)r*2*Cc_ + t*4);
  f32x4 sh = *(const f32x4*)(ss + (size_t)r*2*Cc_ + Cc_ + t*4);
  u16x4 o;
  #pragma unroll
  for(int j=0;j<4;j++){ float hv = (xv[j]-mu)*rstd*(1.f+sc[j]) + sh[j]; o[j] = f2bf(hv); }
  *(u16x4*)(h + (size_t)r*Cc_ + t*4) = o;
}

// ---------------- per-head LN over D=64 + rope, in place; one wave per row (R1-proven form)
__global__ __launch_bounds__(256) void k_lnrope(u16* __restrict__ qp, u16* __restrict__ kp,
                                                const float* __restrict__ tab){
  const int w = threadIdx.x>>6, l = threadIdx.x&63;
  const int row = blockIdx.x*4 + w;                 // 0..B*H*N-1
  u16* p = (blockIdx.y ? kp : qp) + (size_t)row*Dd;
  const int n = row & (Nn-1);
  float v = bf2f(p[l]);
  float s = v, s2 = v*v;
  #pragma unroll
  for(int off=1; off<64; off<<=1){ s += __shfl_xor(s, off); s2 += __shfl_xor(s2, off); }
  float mu = s*(1.f/64.f);
  float rstd = rsqrtf(s2*(1.f/64.f) - mu*mu + 1e-5f);
  float tv = (v - mu)*rstd;
  float pv = __shfl_xor(tv, 32);
  f32x2 cs = ((const f32x2*)tab)[n*32 + (l&31)];
  float o = (l < 32) ? (tv*cs[0] - pv*cs[1]) : (pv*cs[1] + tv*cs[0]);
  p[l] = f2bf(o);
}

// ---------------- V (bh,N,D) -> VT (bh,D,N)
__global__ __launch_bounds__(256) void k_vT(const u16* __restrict__ v, u16* __restrict__ vt){
  __shared__ u32 tile[64][65];
  const int bh = blockIdx.y, n0 = blockIdx.x*64;
  const int t = threadIdx.x;
  const u16* src = v + ((size_t)bh*Nn + n0)*Dd;
  #pragma unroll
  for(int i=0;i<16;i++){ int e = i*256+t; tile[e>>6][e&63] = src[e]; }
  __syncthreads();
  #pragma unroll
  for(int i=0;i<16;i++){ int e = i*256+t; int d = e>>6, n = e&63;
    vt[((size_t)bh*Dd + d)*Nn + n0 + n] = (u16)tile[n][d]; }
}

// ---------------- shared bt-GEMM: C(M x Nc) = A(M x K) @ BT(Nc x K)^T
// T1 bijective XCD swizzle on the flattened block id (all grids are %8==0)
template<int MODE>
__global__ __launch_bounds__(256) void k_gemm(
    const u16* __restrict__ A, const u16* __restrict__ BT, int K, int Nc,
    const float* __restrict__ bias, float* __restrict__ outf,
    u16* __restrict__ qo, u16* __restrict__ ko, u16* __restrict__ vo,
    const float* __restrict__ addend)
{
  __shared__ u16 sA[128*64];
  __shared__ u16 sB[128*64];
  const int t = threadIdx.x, w = t>>6;
  const int lr = t&15, lg = (t&63)>>4;
  const int gx = gridDim.x;
  const int nwg = gx*gridDim.y;
  const int fid = blockIdx.y*gx + blockIdx.x;
  const int sid = (fid&7)*(nwg>>3) + (fid>>3);
  const int row0 = (sid/gx)*128, col0 = (sid%gx)*128;
  const int wm = w>>1, wn = w&1;
  f32x4 acc[4][4] = {};
  for(int k0=0; k0<K; k0+=64){
    #pragma unroll
    for(int c=0;c<4;c++){
      int e = (c*256+t)*8;
      int r = e>>6, ch = (e>>3)&7;
      int sw = ((ch ^ (r&7))<<3);
      const u16* ga = A + (size_t)(row0+r)*K + k0 + sw;
      gld16(ga, (char*)sA + (c*256 + w*64)*16);
      const u16* gb = BT + (size_t)(col0+r)*K + k0 + sw;
      gld16(gb, (char*)sB + (c*256 + w*64)*16);
    }
    asm volatile("s_waitcnt vmcnt(0)" ::: "memory");
    __syncthreads();
    #pragma unroll
    for(int kk=0;kk<2;kk++){
      short8 af[4], bfr[4];
      #pragma unroll
      for(int mi=0;mi<4;mi++){
        int r = wm*64 + mi*16 + lr;
        af[mi] = *(const short8*)(sA + r*64 + (((kk*4+lg) ^ (r&7))<<3));
      }
      #pragma unroll
      for(int ni=0;ni<4;ni++){
        int r = wn*64 + ni*16 + lr;
        bfr[ni] = *(const short8*)(sB + r*64 + (((kk*4+lg) ^ (r&7))<<3));
      }
      #pragma unroll
      for(int mi=0;mi<4;mi++)
        #pragma unroll
        for(int ni=0;ni<4;ni++)
          acc[mi][ni] = __builtin_amdgcn_mfma_f32_16x16x32_bf16(af[mi], bfr[ni], acc[mi][ni], 0,0,0);
    }
    __syncthreads();
  }
  #pragma unroll
  for(int mi=0;mi<4;mi++){
    #pragma unroll
    for(int ni=0;ni<4;ni++){
      #pragma unroll
      for(int j=0;j<4;j++){
        int grow = row0 + wm*64 + mi*16 + lg*4 + j;
        int gcol = col0 + wn*64 + ni*16 + lr;
        float val = acc[mi][ni][j];
        if(MODE==0){
          outf[(size_t)grow*Nc + gcol] = val + bias[gcol];
        } else if(MODE==1){
          int tt = gcol>>10, hh = (gcol>>6)&15, dd = gcol&63;
          int b = grow>>11, n = grow&(Nn-1);
          size_t idx = (((size_t)(b*Hh+hh))*Nn + n)*Dd + dd;
          u16 bv = f2bf(val);
          if(tt==0) qo[idx]=bv; else if(tt==1) ko[idx]=bv; else vo[idx]=bv;
        } else {
          size_t idx = (size_t)grow*Nc + gcol;
          outf[idx] = val + addend[idx];
        }
      }
    }
  }
}

// ---------------- flash attention, swapped-QK^T, NO online max
// LN makes ||q||=||k||=sqrt(D)=8 exactly and RoPE is a rotation, so |q.k| <= 64
// -> |s*cl2| <= 11.7, exp2 in [3e-4, 3300], lsum <= 6.7e6: all safely in f32/bf16 range.
// Softmax is scale-invariant so skipping max-subtraction changes nothing numerically.
// This removes the per-tile max chain + cross-lane max + rescale; o0/o1 are never touched
// by VALU until the epilogue (clean AGPR residency, no accvgpr churn).
__global__ __launch_bounds__(256,3) void k_attn(
    const u16* __restrict__ Q, const u16* __restrict__ Kb,
    const u16* __restrict__ VT, u16* __restrict__ obf, float* __restrict__ of)
{
  __shared__ u16 sK[2][4096];
  __shared__ u16 sV[2][4096];
  const int t = threadIdx.x, w = t>>6, l = t&63;
  const int srow = l&31, hi = l>>5;
  const int id = blockIdx.x;
  const int bh = ((id&7)<<3) | ((id>>3)&7);   // 8 bh per XCD: K/V stays in one L2
  const int q0 = (id>>6)*128;
  const u16* qb = Q  + (size_t)bh*Nn*Dd;
  const u16* kg = Kb + (size_t)bh*Nn*Dd;
  const u16* vg = VT + (size_t)bh*Dd*Nn;

  // Q fragments (B-operand: col=srow -> q, slot (hi,j) -> d = c*16 + hi*8 + j)
  short8 qf[4];
  #pragma unroll
  for(int c=0;c<4;c++)
    qf[c] = *(const short8*)(qb + (size_t)(q0 + w*32 + srow)*Dd + c*16 + hi*8);

  f32x16 o0 = {}, o1 = {};
  float lsum = 0.f;
  const float cl2 = 0.18033688011112042f;   // (1/sqrt(64)) * log2(e)

  const int grow8 = l>>3;
  const int gc = (l&7) ^ grow8;
  const int x7 = l&7;

  // hoisted per-lane LDS byte offsets (loop-invariant)
  int koff[4], voff[8];
  #pragma unroll
  for(int c=0;c<4;c++)  koff[c]  = srow*128 + (((c*2+hi)^x7)<<4);
  #pragma unroll
  for(int cc=0;cc<8;cc++) voff[cc] = srow*128 + ((cc^x7)<<4) + hi*8;

  // per-lane staging source pointer + strides (waves 0,1 stage K; 2,3 stage V)
  const u16* gst; int sI, adv;
  if(w < 2){ gst = kg + (size_t)(w*4)*512 + grow8*64 + gc*8;        sI = 512;   adv = 4096; }
  else     { gst = vg + ((size_t)(w*4-8)*8 + grow8)*Nn + gc*8;      sI = 16384; adv = 64;   }
  char* myLds0 = (w < 2) ? ((char*)&sK[0][0] + w*4096) : ((char*)&sV[0][0] + (w-2)*4096);
  char* myLds1 = myLds0 + 8192;

  auto stage = [&](char* dst){
    #pragma unroll
    for(int i=0;i<4;i++)
      gld16(gst + (size_t)i*sI, dst + i*1024);
    gst += adv;
  };

  auto compute = [&](int BUF){   // BUF is a literal at each call site -> folds after inlining
    const char* sKb = (const char*)&sK[BUF][0];
    const char* sVb = (const char*)&sV[BUF][0];
    // ---- QK^T: s0/s1 = S^T for kv 0..31 / 32..63 of this tile (raw scores)
    f32x16 s0 = {}, s1 = {};
    #pragma unroll
    for(int c=0;c<4;c++){
      short8 kf0 = *(const short8*)(sKb + koff[c]);
      short8 kf1 = *(const short8*)(sKb + koff[c] + 4096);
      s0 = __builtin_amdgcn_mfma_f32_32x32x16_bf16(kf0, qf[c], s0, 0,0,0);
      s1 = __builtin_amdgcn_mfma_f32_32x32x16_bf16(kf1, qf[c], s1, 0,0,0);
    }
    // ---- softmax numerator, no max subtraction (independent exp2 chains)
    float rs = 0.f;
    #pragma unroll
    for(int r=0;r<16;r++){
      float p0 = exp2f(s0[r]*cl2); s0[r] = p0;
      float p1 = exp2f(s1[r]*cl2); s1[r] = p1;
      rs += p0 + p1;
    }
    rs += __shfl_xor(rs, 32);
    lsum += rs;
    // ---- PV: O^T += V-frag x P-frag with lane-local k-slices
    #pragma unroll
    for(int kb=0;kb<2;kb++){
      const f32x16& sp = kb ? s1 : s0;
      union { u32 wd[4]; short8 v; } pA, pB;
      pA.wd[0]=cvtpk(sp[0],sp[1]);   pA.wd[1]=cvtpk(sp[2],sp[3]);
      pA.wd[2]=cvtpk(sp[4],sp[5]);   pA.wd[3]=cvtpk(sp[6],sp[7]);
      pB.wd[0]=cvtpk(sp[8],sp[9]);   pB.wd[1]=cvtpk(sp[10],sp[11]);
      pB.wd[2]=cvtpk(sp[12],sp[13]); pB.wd[3]=cvtpk(sp[14],sp[15]);
      #pragma unroll
      for(int db=0;db<2;db++){
        union { s16x4 h[2]; short8 v; } vA, vB;
        vA.h[0] = *(const s16x4*)(sVb + voff[kb*4+0] + db*4096);
        vA.h[1] = *(const s16x4*)(sVb + voff[kb*4+1] + db*4096);
        vB.h[0] = *(const s16x4*)(sVb + voff[kb*4+2] + db*4096);
        vB.h[1] = *(const s16x4*)(sVb + voff[kb*4+3] + db*4096);
        if(db==0){
          o0 = __builtin_amdgcn_mfma_f32_32x32x16_bf16(vA.v, pA.v, o0, 0,0,0);
          o0 = __builtin_amdgcn_mfma_f32_32x32x16_bf16(vB.v, pB.v, o0, 0,0,0);
        } else {
          o1 = __builtin_amdgcn_mfma_f32_32x32x16_bf16(vA.v, pA.v, o1, 0,0,0);
          o1 = __builtin_amdgcn_mfma_f32_32x32x16_bf16(vB.v, pB.v, o1, 0,0,0);
        }
      }
    }
  };

  // prologue: stage tile 0 into buf0
  stage(myLds0);
  asm volatile("s_waitcnt vmcnt(0)" ::: "memory");
  __syncthreads();

  #pragma unroll 1
  for(int m=0;m<16;m++){
    stage(myLds1);                 // tile 2m+1 -> buf1
    compute(0);                    // tile 2m from buf0
    asm volatile("s_waitcnt vmcnt(0)" ::: "memory");
    __syncthreads();
    if(m < 15) stage(myLds0);      // tile 2m+2 -> buf0
    compute(1);                    // tile 2m+1 from buf1
    asm volatile("s_waitcnt vmcnt(0)" ::: "memory");
    __syncthreads();
  }

  // ---- epilogue: lane owns O[q=q0+w*32+srow][d = (r&3)+8(r>>2)+4hi + 32db]
  float rl = 1.0f / lsum;
  const int n = q0 + w*32 + srow;
  const int b = bh>>4, hh = bh&15;
  size_t base = ((size_t)(b*Nn + n))*Cc_ + hh*Dd;
  #pragma unroll
  for(int db=0;db<2;db++){
    const f32x16& oo = db ? o1 : o0;
    #pragma unroll
    for(int mb=0;mb<4;mb++){
      int d0 = db*32 + mb*8 + hi*4;
      f32x4 v4; u16x4 h4;
      #pragma unroll
      for(int j=0;j<4;j++){ float v = oo[mb*4+j]*rl; v4[j] = v; h4[j] = f2bf(v); }
      *(f32x4*)(of + base + d0) = v4;
      *(u16x4*)(obf + base + d0) = h4;
    }
  }
}

extern "C" void kernel_launch(void* const* d_in, const int* in_sizes, int n_in,
                              void* d_out, int out_size, void* d_ws, size_t ws_size,
                              hipStream_t stream){
  const float* x      = (const float*)d_in[0];
  const float* emb    = (const float*)d_in[1];
  const float* emb_w  = (const float*)d_in[2];
  const float* emb_b  = (const float*)d_in[3];
  const float* proj_w = (const float*)d_in[4];
  const float* out_w  = (const float*)d_in[5];
  float* out = (float*)d_out;
  char* ws = (char*)d_ws;
  size_t off = 0;
  auto alloc = [&](size_t bytes)->char*{ char* p = ws + off; off += (bytes+255)&~(size_t)255; return p; };

  u16*  embbf = (u16*)alloc((size_t)Mm*Cc_*2);        // 16MB; reused as vT after GEMM1
  u16*  wT_e  = (u16*)alloc((size_t)2*Cc_*Cc_*2);     // 4MB
  u16*  wT_p  = (u16*)alloc((size_t)3*Cc_*Cc_*2);     // 6MB
  u16*  wT_o  = (u16*)alloc((size_t)Cc_*Cc_*2);       // 2MB
  float* ss   = (float*)alloc((size_t)Mm*2*Cc_*4);    // 64MB; reused as of+obf after ln_mod
  u16*  h     = (u16*)alloc((size_t)Mm*Cc_*2);        // 16MB
  u16*  qB    = (u16*)alloc((size_t)Mm*Cc_*2);        // 16MB
  u16*  kB    = (u16*)alloc((size_t)Mm*Cc_*2);        // 16MB
  u16*  vB    = (u16*)alloc((size_t)Mm*Cc_*2);        // 16MB
  float* tab  = (float*)alloc((size_t)Nn*32*8);       // 512KB

  u16*  vT  = embbf;                                  // alias (embbf dead after GEMM1)
  float* of  = ss;                                    // alias (ss dead after ln_mod)
  u16*  obf = (u16*)((char*)ss + (size_t)Mm*Cc_*4);

  kT_cvt<<<dim3(32,16),256,0,stream>>>(emb_w,  wT_e, Cc_, 2*Cc_);
  kT_cvt<<<dim3(48,16),256,0,stream>>>(proj_w, wT_p, Cc_, 3*Cc_);
  kT_cvt<<<dim3(16,16),256,0,stream>>>(out_w,  wT_o, Cc_, Cc_);
  k_cvt<<<8192,256,0,stream>>>(emb, embbf, Mm*Cc_);
  k_ropetab<<<256,256,0,stream>>>(tab);
  k_gemm<0><<<dim3(16,64),256,0,stream>>>(embbf, wT_e, Cc_, 2*Cc_, emb_b, ss,
                                          nullptr,nullptr,nullptr, nullptr);
  k_ln_mod<<<Mm,256,0,stream>>>(x, ss, h);
  k_gemm<1><<<dim3(24,64),256,0,stream>>>(h, wT_p, Cc_, 3*Cc_, nullptr, nullptr,
                                          qB, kB, vB, nullptr);
  k_lnrope<<<dim3(32768,2),256,0,stream>>>(qB, kB, tab);
  k_vT<<<dim3(32,64),256,0,stream>>>(vB, vT);
  k_attn<<<1024,256,0,stream>>>(qB, kB, vT, obf, of);
  k_gemm<2><<<dim3(8,64),256,0,stream>>>(obf, wT_o, Cc_, Cc_, nullptr, out,
                                         nullptr,nullptr,nullptr, of);
}